// Round 6
// baseline (289.849 us; speedup 1.0000x reference)
//
#include <hip/hip_runtime.h>
#include <hip/hip_fp16.h>

// GIN: 2x GINConv(eps=0, MLP 2-layer H=64) + global mean pool + linear.
// N=50000, E=800000, G=2500.
//
// R5: fill_csr (55us, 52MB write-through from random 4B scatter) replaced by
// two-pass binned fill: bin_pairs groups edges into 512-node buckets with
// contiguous-run writes; fill_csr2 scatters within one bucket's ~65KB window
// using LDS per-node cursors. pairs aliases the z scratch (no ws growth).

typedef unsigned int uint;
typedef unsigned long long ull;

#define BSH  9           // bucket = 512 nodes
#define NBKMAX 128       // >= ceil(50000/512)=98

__device__ __forceinline__ float rlane(float v, int k) {
    return __uint_as_float(__builtin_amdgcn_readlane(__float_as_uint(v), k));
}

// ---------------- degree + bucket histogram ----------------

__global__ __launch_bounds__(256) void count_deg(
    const int* __restrict__ dst, int* __restrict__ deg,
    int* __restrict__ bkt_cnt, int nbk, int E)
{
    __shared__ int lb[NBKMAX];
    for (int i = threadIdx.x; i < nbk; i += 256) lb[i] = 0;
    __syncthreads();
    int e0 = blockIdx.x * 1024 + threadIdx.x;
#pragma unroll
    for (int j = 0; j < 4; j++) {
        int e = e0 + j * 256;
        if (e < E) {
            int d = dst[e];
            atomicAdd(&deg[d], 1);
            atomicAdd(&lb[d >> BSH], 1);
        }
    }
    __syncthreads();
    if (threadIdx.x < nbk) {
        int c = lb[threadIdx.x];
        if (c) atomicAdd(&bkt_cnt[threadIdx.x], c);
    }
}

// ---------------- node-offset scan (hierarchical) ----------------

__global__ __launch_bounds__(256) void scan1(
    const int* __restrict__ deg, int* __restrict__ offs,
    int* __restrict__ bsum, int N)
{
    __shared__ int wsum[4];
    int i = blockIdx.x * 256 + threadIdx.x;
    int v = (i < N) ? deg[i] : 0;
    int lane = threadIdx.x & 63, w = threadIdx.x >> 6;
    int s = v;
#pragma unroll
    for (int off = 1; off < 64; off <<= 1) {
        int t = __shfl_up(s, off, 64);
        if (lane >= off) s += t;
    }
    if (lane == 63) wsum[w] = s;
    __syncthreads();
    int add = 0;
    for (int j = 0; j < w; j++) add += wsum[j];
    int incl = s + add;
    if (i < N) offs[i] = incl - v;
    if (threadIdx.x == 255) bsum[blockIdx.x] = incl;
}

__global__ __launch_bounds__(256) void scan2(int* __restrict__ bsum, int NB)
{
    __shared__ int wsum[4];
    int i = threadIdx.x;
    int v = (i < NB) ? bsum[i] : 0;
    int lane = threadIdx.x & 63, w = threadIdx.x >> 6;
    int s = v;
#pragma unroll
    for (int off = 1; off < 64; off <<= 1) {
        int t = __shfl_up(s, off, 64);
        if (lane >= off) s += t;
    }
    if (lane == 63) wsum[w] = s;
    __syncthreads();
    int add = 0;
    for (int j = 0; j < w; j++) add += wsum[j];
    int incl = s + add;
    if (i < NB) bsum[i] = incl - v;
}

__global__ __launch_bounds__(256) void scan3(
    int* __restrict__ offs, const int* __restrict__ bsum, int N)
{
    int i = blockIdx.x * 256 + threadIdx.x;
    if (i < N) offs[i] += bsum[blockIdx.x];
}

// ---------------- bucket-offset scan (single block) ----------------

__global__ __launch_bounds__(256) void scan_small(
    const int* __restrict__ cnt, int* __restrict__ off,
    int* __restrict__ cur, int nbk)
{
    __shared__ int wsum[4];
    int i = threadIdx.x;
    int v = (i < nbk) ? cnt[i] : 0;
    int lane = threadIdx.x & 63, w = threadIdx.x >> 6;
    int s = v;
#pragma unroll
    for (int off2 = 1; off2 < 64; off2 <<= 1) {
        int t = __shfl_up(s, off2, 64);
        if (lane >= off2) s += t;
    }
    if (lane == 63) wsum[w] = s;
    __syncthreads();
    int add = 0;
    for (int j = 0; j < w; j++) add += wsum[j];
    int incl = s + add;
    if (i < nbk) { off[i] = incl - v; cur[i] = incl - v; }
    if (i == nbk - 1) off[nbk] = incl;   // == E
}

// ---------------- pass 1: bin edges into bucket-contiguous runs ----------------

__global__ __launch_bounds__(256) void bin_pairs(
    const int* __restrict__ src, const int* __restrict__ dst,
    int* __restrict__ bkt_cur, ull* __restrict__ pairs, int nbk, int E)
{
    __shared__ int lcnt[NBKMAX];
    __shared__ int lbase[NBKMAX];
    for (int i = threadIdx.x; i < nbk; i += 256) lcnt[i] = 0;
    __syncthreads();
    int e0 = blockIdx.x * 1024 + threadIdx.x;
    int sv[4], dv[4], rk[4], bk[4];
#pragma unroll
    for (int j = 0; j < 4; j++) {
        int e = e0 + j * 256;
        bk[j] = -1;
        if (e < E) {
            sv[j] = src[e];
            dv[j] = dst[e];
            bk[j] = dv[j] >> BSH;
            rk[j] = atomicAdd(&lcnt[bk[j]], 1);
        }
    }
    __syncthreads();
    if (threadIdx.x < nbk) {
        int c = lcnt[threadIdx.x];
        lbase[threadIdx.x] = c ? atomicAdd(&bkt_cur[threadIdx.x], c) : 0;
    }
    __syncthreads();
#pragma unroll
    for (int j = 0; j < 4; j++) {
        if (bk[j] >= 0)
            pairs[(size_t)lbase[bk[j]] + rk[j]] =
                ((ull)(uint)dv[j] << 32) | (uint)sv[j];
    }
}

// ---------------- pass 2: scatter within bucket window (LDS cursors) ----------

__global__ __launch_bounds__(256) void fill_csr2(
    const ull* __restrict__ pairs, const int* __restrict__ bkt_off,
    const int* __restrict__ offs, int* __restrict__ ssrc, int N)
{
    __shared__ int cur[1 << BSH];
    int b = blockIdx.x;
    int nbase = b << BSH;
    int nn = min(1 << BSH, N - nbase);
    for (int j = threadIdx.x; j < nn; j += 256) cur[j] = offs[nbase + j];
    __syncthreads();
    int start = bkt_off[b], end = bkt_off[b + 1];
    for (int e = start + threadIdx.x; e < end; e += 256) {
        ull pr = pairs[e];
        int s = (int)(uint)pr;
        int d = (int)(pr >> 32);
        int p = atomicAdd(&cur[d - nbase], 1);
        ssrc[p] = s;
    }
}

// ---------------- gather1: z0 = self + sum_nbr concat(x,pos), f32 [N x 16] ----

__global__ __launch_bounds__(256) void gather1(
    const float* __restrict__ x, const float* __restrict__ pos,
    const int* __restrict__ offs, const int* __restrict__ deg,
    const int* __restrict__ ssrc,
    float* __restrict__ z0, int N)
{
    int lane = threadIdx.x & 63;
    int i = blockIdx.x * 4 + (threadIdx.x >> 6);
    if (i >= N) return;
    int f = lane & 15, sub = lane >> 4;
    int st = offs[i], len = deg[i];
    float a0 = 0.f, a1 = 0.f;
    int k = 0;
    while (k < len) {
        int chunk = min(len - k, 64);
        int sv = ssrc[st + k + min(lane, chunk - 1)];
        int m = 0;
        for (; m + 8 <= chunk; m += 8) {
            int sA = __shfl(sv, m + sub, 64);
            int sB = __shfl(sv, m + 4 + sub, 64);
            if (f < 14) {
                a0 += (f < 11) ? x[sA * 11 + f] : pos[sA * 3 + (f - 11)];
                a1 += (f < 11) ? x[sB * 11 + f] : pos[sB * 3 + (f - 11)];
            }
        }
        for (; m < chunk; m += 4) {
            int jj = m + sub;
            int s = __shfl(sv, (jj < chunk) ? jj : 0, 64);
            if (jj < chunk && f < 14)
                a0 += (f < 11) ? x[s * 11 + f] : pos[s * 3 + (f - 11)];
        }
        k += chunk;
    }
    float a = a0 + a1;
    a += __shfl_xor(a, 16, 64);
    a += __shfl_xor(a, 32, 64);
    if (f < 14) a += (f < 11) ? x[i * 11 + f] : pos[i * 3 + (f - 11)];
    if (lane < 16) z0[(size_t)i * 16 + lane] = (lane < 14) ? a : 0.f;
}

// ---------------- mlp1: h1 = relu(MLP(z0)) -> packed f16 [N x 32 dwords] ----

__global__ __launch_bounds__(256) void mlp1(
    const float* __restrict__ z0,
    const float* __restrict__ W1a, const float* __restrict__ b1a,
    const float* __restrict__ W1b, const float* __restrict__ b1b,
    uint* __restrict__ h1p, int N)
{
    __shared__ float Wa[14 * 64];
    __shared__ float Wb[64 * 64];
    for (int i = threadIdx.x; i < 14 * 64; i += 256) Wa[i] = W1a[i];
    for (int i = threadIdx.x; i < 64 * 64; i += 256) Wb[i] = W1b[i];
    __syncthreads();

    int lane = threadIdx.x & 63;
    int wv = blockIdx.x * 4 + (threadIdx.x >> 6);
    int i0 = wv * 4;
    if (i0 >= N) return;

    float zl = z0[(size_t)i0 * 16 + lane];
    float ba = b1a[lane], bb = b1b[lane];

    float t[4], o[4];
#pragma unroll
    for (int n = 0; n < 4; n++) t[n] = ba;
#pragma unroll
    for (int k = 0; k < 14; k++) {
        float wa = Wa[k * 64 + lane];
#pragma unroll
        for (int n = 0; n < 4; n++) t[n] += rlane(zl, n * 16 + k) * wa;
    }
#pragma unroll
    for (int n = 0; n < 4; n++) { t[n] = fmaxf(t[n], 0.f); o[n] = bb; }
#pragma unroll
    for (int k = 0; k < 64; k++) {
        float wb = Wb[k * 64 + lane];
#pragma unroll
        for (int n = 0; n < 4; n++) o[n] += rlane(t[n], k) * wb;
    }
#pragma unroll
    for (int n = 0; n < 4; n++) o[n] = fmaxf(o[n], 0.f);  // outer relu L1

    int p = lane & 31, half = lane >> 5;
#pragma unroll
    for (int pr = 0; pr < 2; pr++) {
        float lo0 = __shfl(o[2 * pr],     2 * p,     64);
        float hi0 = __shfl(o[2 * pr],     2 * p + 1, 64);
        float lo1 = __shfl(o[2 * pr + 1], 2 * p,     64);
        float hi1 = __shfl(o[2 * pr + 1], 2 * p + 1, 64);
        float lo = half ? lo1 : lo0;
        float hi = half ? hi1 : hi0;
        __half2 h = __halves2half2(__float2half(lo), __float2half(hi));
        h1p[(size_t)(i0 + 2 * pr + half) * 32 + p] = *(uint*)&h;
    }
}

// ---------------- gather2: z1 = self + sum_nbr h1 -> packed f16 [N x 32] ----

__global__ __launch_bounds__(256) void gather2(
    const uint* __restrict__ h1p,
    const int* __restrict__ offs, const int* __restrict__ deg,
    const int* __restrict__ ssrc,
    uint* __restrict__ z1p, int N)
{
    int lane = threadIdx.x & 63;
    int i = blockIdx.x * 4 + (threadIdx.x >> 6);
    if (i >= N) return;
    int p = lane & 31, half = lane >> 5;
    int st = offs[i], len = deg[i];
    float c0l = 0.f, c0h = 0.f, c1l = 0.f, c1h = 0.f;
    float c2l = 0.f, c2h = 0.f, c3l = 0.f, c3h = 0.f;
    int k = 0;
    while (k < len) {
        int chunk = min(len - k, 64);
        int sv = ssrc[st + k + min(lane, chunk - 1)];
        int t = 0;
        for (; t + 8 <= chunk; t += 8) {
            int s0 = __shfl(sv, t     + half, 64);
            int s1 = __shfl(sv, t + 2 + half, 64);
            int s2 = __shfl(sv, t + 4 + half, 64);
            int s3 = __shfl(sv, t + 6 + half, 64);
            uint d0 = h1p[(size_t)s0 * 32 + p];
            uint d1 = h1p[(size_t)s1 * 32 + p];
            uint d2 = h1p[(size_t)s2 * 32 + p];
            uint d3 = h1p[(size_t)s3 * 32 + p];
            __half2 h0 = *(__half2*)&d0, h1_ = *(__half2*)&d1;
            __half2 h2 = *(__half2*)&d2, h3 = *(__half2*)&d3;
            c0l += __low2float(h0); c0h += __high2float(h0);
            c1l += __low2float(h1_); c1h += __high2float(h1_);
            c2l += __low2float(h2); c2h += __high2float(h2);
            c3l += __low2float(h3); c3h += __high2float(h3);
        }
        for (; t + 2 <= chunk; t += 2) {
            int s0 = __shfl(sv, t + half, 64);
            uint d0 = h1p[(size_t)s0 * 32 + p];
            __half2 h0 = *(__half2*)&d0;
            c0l += __low2float(h0); c0h += __high2float(h0);
        }
        if (t < chunk) {
            int s0 = __shfl(sv, t, 64);
            uint d0 = h1p[(size_t)s0 * 32 + p];
            __half2 h0 = *(__half2*)&d0;
            if (half == 0) { c0l += __low2float(h0); c0h += __high2float(h0); }
        }
        k += chunk;
    }
    float zl = (c0l + c1l) + (c2l + c3l);
    float zh = (c0h + c1h) + (c2h + c3h);
    zl += __shfl_xor(zl, 32, 64);
    zh += __shfl_xor(zh, 32, 64);
    uint ds = h1p[(size_t)i * 32 + p];
    __half2 hs = *(__half2*)&ds;
    zl += __low2float(hs);
    zh += __high2float(hs);
    if (half == 0) {
        __half2 zo = __halves2half2(__float2half(zl), __float2half(zh));
        z1p[(size_t)i * 32 + p] = *(uint*)&zo;
    }
}

// ---------------- mlp2 + pooling ----------------

__global__ __launch_bounds__(256) void mlp2pool(
    const uint* __restrict__ z1p,
    const float* __restrict__ W2a, const float* __restrict__ b2a,
    const float* __restrict__ W2b, const float* __restrict__ b2b,
    const int* __restrict__ batch,
    float* __restrict__ sums, float* __restrict__ counts, int N)
{
    __shared__ float Wa[64 * 64];
    __shared__ float Wb[64 * 64];
    for (int i = threadIdx.x; i < 64 * 64; i += 256) {
        Wa[i] = W2a[i];
        Wb[i] = W2b[i];
    }
    __syncthreads();

    int lane = threadIdx.x & 63;
    int wv = blockIdx.x * 4 + (threadIdx.x >> 6);
    int i0 = wv * 4;
    if (i0 >= N) return;
    float ba = b2a[lane], bb = b2b[lane];

    float zl[4];
#pragma unroll
    for (int n = 0; n < 4; n++) {
        uint d = z1p[(size_t)(i0 + n) * 32 + (lane >> 1)];
        __half2 h = *(__half2*)&d;
        zl[n] = (lane & 1) ? __high2float(h) : __low2float(h);
    }

    float t[4], o[4];
#pragma unroll
    for (int n = 0; n < 4; n++) t[n] = ba;
#pragma unroll
    for (int k = 0; k < 64; k++) {
        float wa = Wa[k * 64 + lane];
#pragma unroll
        for (int n = 0; n < 4; n++) t[n] += rlane(zl[n], k) * wa;
    }
#pragma unroll
    for (int n = 0; n < 4; n++) { t[n] = fmaxf(t[n], 0.f); o[n] = bb; }
#pragma unroll
    for (int k = 0; k < 64; k++) {
        float wb = Wb[k * 64 + lane];
#pragma unroll
        for (int n = 0; n < 4; n++) o[n] += rlane(t[n], k) * wb;
    }

    int gcur = batch[i0]; float ps = 0.f; int cnt = 0;
#pragma unroll
    for (int n = 0; n < 4; n++) {
        float h2 = fmaxf(o[n], 0.f);
        int gi = batch[i0 + n];
        if (gi != gcur) {
            atomicAdd(&sums[gcur * 64 + lane], ps);
            if (lane == 0) atomicAdd(&counts[gcur], (float)cnt);
            gcur = gi; ps = 0.f; cnt = 0;
        }
        ps += h2; cnt++;
    }
    atomicAdd(&sums[gcur * 64 + lane], ps);
    if (lane == 0) atomicAdd(&counts[gcur], (float)cnt);
}

__global__ __launch_bounds__(256) void gin_final(
    const float* __restrict__ sums, const float* __restrict__ counts,
    const float* __restrict__ Wlin, const float* __restrict__ blin,
    float* __restrict__ out, int G)
{
    int lane = threadIdx.x & 63;
    int g    = blockIdx.x * 4 + (threadIdx.x >> 6);
    if (g < G) {
        float v = sums[g * 64 + lane] * Wlin[lane];
#pragma unroll
        for (int off = 32; off > 0; off >>= 1) v += __shfl_down(v, off, 64);
        if (lane == 0) out[g] = v / fmaxf(counts[g], 1.0f) + blin[0];
    }
}

extern "C" void kernel_launch(void* const* d_in, const int* in_sizes, int n_in,
                              void* d_out, int out_size, void* d_ws, size_t ws_size,
                              hipStream_t stream) {
    const float* x    = (const float*)d_in[0];
    const float* pos  = (const float*)d_in[1];
    const int*   ei   = (const int*)d_in[2];
    const int*   batch= (const int*)d_in[3];
    const float* W1a  = (const float*)d_in[4];
    const float* b1a  = (const float*)d_in[5];
    const float* W1b  = (const float*)d_in[6];
    const float* b1b  = (const float*)d_in[7];
    const float* W2a  = (const float*)d_in[8];
    const float* b2a  = (const float*)d_in[9];
    const float* W2b  = (const float*)d_in[10];
    const float* b2b  = (const float*)d_in[11];
    const float* Wlin = (const float*)d_in[12];
    const float* blin = (const float*)d_in[13];
    float* out = (float*)d_out;

    const int N = in_sizes[0] / 11;     // 50000
    const int E = in_sizes[2] / 2;      // 800000
    const int G = out_size;             // 2500

    const int* src = ei;
    const int* dst = ei + E;
    const int NB  = (N + 255) / 256;
    const int nbk = (N + (1 << BSH) - 1) >> BSH;   // 98

    // Workspace:
    // [deg|sums|counts|bkt_cnt](memset) |offs|bsum|bkt_off|bkt_cur|ssrc|h1p|
    // zreg { z0 (N*16 f32) / z1p (N*32 u32) / pairs (E ull) } -- time-disjoint
    char* ws = (char*)d_ws;
    size_t o = 0;
    int*   deg     = (int*)(ws + o);   o += (size_t)N * 4;
    float* sums    = (float*)(ws + o); o += (size_t)G * 64 * 4;
    float* counts  = (float*)(ws + o); o += (((size_t)G + 63) & ~(size_t)63) * 4;
    int*   bkt_cnt = (int*)(ws + o);   o += NBKMAX * 4;
    size_t zero_bytes = o;
    int*   offs    = (int*)(ws + o);   o += (size_t)N * 4;
    int*   bsum    = (int*)(ws + o);   o += 256 * 4;
    int*   bkt_off = (int*)(ws + o);   o += (NBKMAX + 1) * 4;
    int*   bkt_cur = (int*)(ws + o);   o += NBKMAX * 4;
    int*   ssrc    = (int*)(ws + o);   o += (size_t)E * 4;
    o = (o + 255) & ~(size_t)255;
    uint*  h1p     = (uint*)(ws + o);  o += (size_t)N * 32 * 4;
    o = (o + 255) & ~(size_t)255;
    float* z0      = (float*)(ws + o); // N*16 f32 (3.2 MB)
    uint*  z1p     = (uint*)(ws + o);  // N*32 u32 (6.4 MB)
    ull*   pairs   = (ull*)(ws + o);   // E*8 B (6.4 MB) -- dead before gather1

    hipMemsetAsync(ws, 0, zero_bytes, stream);

    count_deg<<<(E + 1023) / 1024, 256, 0, stream>>>(dst, deg, bkt_cnt, nbk, E);
    scan1<<<NB, 256, 0, stream>>>(deg, offs, bsum, N);
    scan2<<<1, 256, 0, stream>>>(bsum, NB);
    scan3<<<NB, 256, 0, stream>>>(offs, bsum, N);
    scan_small<<<1, 256, 0, stream>>>(bkt_cnt, bkt_off, bkt_cur, nbk);
    bin_pairs<<<(E + 1023) / 1024, 256, 0, stream>>>(
        src, dst, bkt_cur, pairs, nbk, E);
    fill_csr2<<<nbk, 256, 0, stream>>>(pairs, bkt_off, offs, ssrc, N);

    gather1<<<(N + 3) / 4, 256, 0, stream>>>(x, pos, offs, deg, ssrc, z0, N);
    mlp1<<<(N + 15) / 16, 256, 0, stream>>>(z0, W1a, b1a, W1b, b1b, h1p, N);
    gather2<<<(N + 3) / 4, 256, 0, stream>>>(h1p, offs, deg, ssrc, z1p, N);
    mlp2pool<<<(N + 15) / 16, 256, 0, stream>>>(
        z1p, W2a, b2a, W2b, b2b, batch, sums, counts, N);

    gin_final<<<(G + 3) / 4, 256, 0, stream>>>(
        sums, counts, Wlin, blin, out, G);
}

// Round 7
// 231.075 us; speedup vs baseline: 1.2544x; 1.2544x over previous
//
#include <hip/hip_runtime.h>
#include <hip/hip_fp16.h>

// GIN: 2x GINConv(eps=0, MLP 2-layer H=64) + global mean pool + linear.
// N=50000, E=800000, G=2500.
//
// R6: CSR build with ZERO per-edge global atomics. Nodes are partitioned in
// order into 256-node buckets, so bkt_off[b] (edge count in earlier buckets)
// IS the CSR offset of the bucket's first node. bucket_hist -> scan_small ->
// bin_pairs (4096 edges/block, bucket-contiguous runs) -> bucket_build (one
// block per bucket: LDS deg-hist + LDS scan -> dense deg/offs write + LDS-
// cursor scatter of ssrc into the bucket's ~16KB window). Replaces count_deg
// (47us of global atomics) + scan1/2/3 + fill_csr.

typedef unsigned int uint;
typedef unsigned long long ull;

#define BSH  8           // bucket = 256 nodes
#define NBKMAX 256       // >= ceil(50000/256)=196
#define EPB  4096        // edges per block in hist/bin passes

__device__ __forceinline__ float rlane(float v, int k) {
    return __uint_as_float(__builtin_amdgcn_readlane(__float_as_uint(v), k));
}

// ---------------- bucket histogram (LDS-privatized) ----------------

__global__ __launch_bounds__(256) void bucket_hist(
    const int* __restrict__ dst, int* __restrict__ bkt_cnt, int nbk, int E)
{
    __shared__ int lb[NBKMAX];
    for (int i = threadIdx.x; i < nbk; i += 256) lb[i] = 0;
    __syncthreads();
    int e0 = blockIdx.x * EPB + threadIdx.x;
#pragma unroll
    for (int j = 0; j < EPB / 256; j++) {
        int e = e0 + j * 256;
        if (e < E) atomicAdd(&lb[dst[e] >> BSH], 1);
    }
    __syncthreads();
    for (int i = threadIdx.x; i < nbk; i += 256) {
        int c = lb[i];
        if (c) atomicAdd(&bkt_cnt[i], c);
    }
}

// ---------------- bucket-offset scan (single block) ----------------

__global__ __launch_bounds__(256) void scan_small(
    const int* __restrict__ cnt, int* __restrict__ off,
    int* __restrict__ cur, int nbk)
{
    __shared__ int wsum[4];
    int i = threadIdx.x;
    int v = (i < nbk) ? cnt[i] : 0;
    int lane = threadIdx.x & 63, w = threadIdx.x >> 6;
    int s = v;
#pragma unroll
    for (int off2 = 1; off2 < 64; off2 <<= 1) {
        int t = __shfl_up(s, off2, 64);
        if (lane >= off2) s += t;
    }
    if (lane == 63) wsum[w] = s;
    __syncthreads();
    int add = 0;
    for (int j = 0; j < w; j++) add += wsum[j];
    int incl = s + add;
    if (i < nbk) { off[i] = incl - v; cur[i] = incl - v; }
    if (i == nbk - 1) off[nbk] = incl;   // == E
}

// ---------------- pass 1: bin edges into bucket-contiguous runs ----------------

__global__ __launch_bounds__(256) void bin_pairs(
    const int* __restrict__ src, const int* __restrict__ dst,
    int* __restrict__ bkt_cur, ull* __restrict__ pairs, int nbk, int E)
{
    __shared__ int lcnt[NBKMAX];
    __shared__ int lbase[NBKMAX];
    for (int i = threadIdx.x; i < nbk; i += 256) lcnt[i] = 0;
    __syncthreads();
    int e0 = blockIdx.x * EPB + threadIdx.x;
    int sv[EPB / 256], dv[EPB / 256], rk[EPB / 256], bk[EPB / 256];
#pragma unroll
    for (int j = 0; j < EPB / 256; j++) {
        int e = e0 + j * 256;
        bk[j] = -1;
        if (e < E) {
            sv[j] = src[e];
            dv[j] = dst[e];
            bk[j] = dv[j] >> BSH;
            rk[j] = atomicAdd(&lcnt[bk[j]], 1);
        }
    }
    __syncthreads();
    for (int i = threadIdx.x; i < nbk; i += 256) {
        int c = lcnt[i];
        lbase[i] = c ? atomicAdd(&bkt_cur[i], c) : 0;
    }
    __syncthreads();
#pragma unroll
    for (int j = 0; j < EPB / 256; j++) {
        if (bk[j] >= 0)
            pairs[(size_t)lbase[bk[j]] + rk[j]] =
                ((ull)(uint)dv[j] << 32) | (uint)sv[j];
    }
}

// ---------------- pass 2: per-bucket deg/offs/ssrc (all LDS-local) ----------

__global__ __launch_bounds__(256) void bucket_build(
    const ull* __restrict__ pairs, const int* __restrict__ bkt_off,
    int* __restrict__ offs, int* __restrict__ deg,
    int* __restrict__ ssrc, int N)
{
    __shared__ int cnt[1 << BSH];
    __shared__ int cur[1 << BSH];
    __shared__ int wsum[4];
    int b = blockIdx.x;
    int nbase = b << BSH;
    int nn = min(1 << BSH, N - nbase);
    cnt[threadIdx.x] = 0;
    __syncthreads();
    int start = bkt_off[b], end = bkt_off[b + 1];
    for (int e = start + threadIdx.x; e < end; e += 256)
        atomicAdd(&cnt[(int)(pairs[e] >> 32) - nbase], 1);
    __syncthreads();
    // exclusive scan of cnt[256] -> global offsets
    int v = cnt[threadIdx.x];
    int lane = threadIdx.x & 63, w = threadIdx.x >> 6;
    int s = v;
#pragma unroll
    for (int off2 = 1; off2 < 64; off2 <<= 1) {
        int t = __shfl_up(s, off2, 64);
        if (lane >= off2) s += t;
    }
    if (lane == 63) wsum[w] = s;
    __syncthreads();
    int add = 0;
    for (int j = 0; j < w; j++) add += wsum[j];
    int gofs = start + (s + add - v);          // global CSR offset
    if (threadIdx.x < nn) {
        offs[nbase + threadIdx.x] = gofs;
        deg[nbase + threadIdx.x]  = v;
    }
    cur[threadIdx.x] = gofs;
    __syncthreads();
    for (int e = start + threadIdx.x; e < end; e += 256) {
        ull pr = pairs[e];
        int d = (int)(pr >> 32) - nbase;
        int p = atomicAdd(&cur[d], 1);
        ssrc[p] = (int)(uint)pr;
    }
}

// ---------------- gather1: z0 = self + sum_nbr concat(x,pos), f32 [N x 16] ----

__global__ __launch_bounds__(256) void gather1(
    const float* __restrict__ x, const float* __restrict__ pos,
    const int* __restrict__ offs, const int* __restrict__ deg,
    const int* __restrict__ ssrc,
    float* __restrict__ z0, int N)
{
    int lane = threadIdx.x & 63;
    int i = blockIdx.x * 4 + (threadIdx.x >> 6);
    if (i >= N) return;
    int f = lane & 15, sub = lane >> 4;
    int st = offs[i], len = deg[i];
    float a0 = 0.f, a1 = 0.f;
    int k = 0;
    while (k < len) {
        int chunk = min(len - k, 64);
        int sv = ssrc[st + k + min(lane, chunk - 1)];
        int m = 0;
        for (; m + 8 <= chunk; m += 8) {
            int sA = __shfl(sv, m + sub, 64);
            int sB = __shfl(sv, m + 4 + sub, 64);
            if (f < 14) {
                a0 += (f < 11) ? x[sA * 11 + f] : pos[sA * 3 + (f - 11)];
                a1 += (f < 11) ? x[sB * 11 + f] : pos[sB * 3 + (f - 11)];
            }
        }
        for (; m < chunk; m += 4) {
            int jj = m + sub;
            int s = __shfl(sv, (jj < chunk) ? jj : 0, 64);
            if (jj < chunk && f < 14)
                a0 += (f < 11) ? x[s * 11 + f] : pos[s * 3 + (f - 11)];
        }
        k += chunk;
    }
    float a = a0 + a1;
    a += __shfl_xor(a, 16, 64);
    a += __shfl_xor(a, 32, 64);
    if (f < 14) a += (f < 11) ? x[i * 11 + f] : pos[i * 3 + (f - 11)];
    if (lane < 16) z0[(size_t)i * 16 + lane] = (lane < 14) ? a : 0.f;
}

// ---------------- mlp1: h1 = relu(MLP(z0)) -> packed f16 [N x 32 dwords] ----

__global__ __launch_bounds__(256) void mlp1(
    const float* __restrict__ z0,
    const float* __restrict__ W1a, const float* __restrict__ b1a,
    const float* __restrict__ W1b, const float* __restrict__ b1b,
    uint* __restrict__ h1p, int N)
{
    __shared__ float Wa[14 * 64];
    __shared__ float Wb[64 * 64];
    for (int i = threadIdx.x; i < 14 * 64; i += 256) Wa[i] = W1a[i];
    for (int i = threadIdx.x; i < 64 * 64; i += 256) Wb[i] = W1b[i];
    __syncthreads();

    int lane = threadIdx.x & 63;
    int wv = blockIdx.x * 4 + (threadIdx.x >> 6);
    int i0 = wv * 4;
    if (i0 >= N) return;

    float zl = z0[(size_t)i0 * 16 + lane];
    float ba = b1a[lane], bb = b1b[lane];

    float t[4], o[4];
#pragma unroll
    for (int n = 0; n < 4; n++) t[n] = ba;
#pragma unroll
    for (int k = 0; k < 14; k++) {
        float wa = Wa[k * 64 + lane];
#pragma unroll
        for (int n = 0; n < 4; n++) t[n] += rlane(zl, n * 16 + k) * wa;
    }
#pragma unroll
    for (int n = 0; n < 4; n++) { t[n] = fmaxf(t[n], 0.f); o[n] = bb; }
#pragma unroll
    for (int k = 0; k < 64; k++) {
        float wb = Wb[k * 64 + lane];
#pragma unroll
        for (int n = 0; n < 4; n++) o[n] += rlane(t[n], k) * wb;
    }
#pragma unroll
    for (int n = 0; n < 4; n++) o[n] = fmaxf(o[n], 0.f);  // outer relu L1

    int p = lane & 31, half = lane >> 5;
#pragma unroll
    for (int pr = 0; pr < 2; pr++) {
        float lo0 = __shfl(o[2 * pr],     2 * p,     64);
        float hi0 = __shfl(o[2 * pr],     2 * p + 1, 64);
        float lo1 = __shfl(o[2 * pr + 1], 2 * p,     64);
        float hi1 = __shfl(o[2 * pr + 1], 2 * p + 1, 64);
        float lo = half ? lo1 : lo0;
        float hi = half ? hi1 : hi0;
        __half2 h = __halves2half2(__float2half(lo), __float2half(hi));
        h1p[(size_t)(i0 + 2 * pr + half) * 32 + p] = *(uint*)&h;
    }
}

// ---------------- gather2: z1 = self + sum_nbr h1 -> packed f16 [N x 32] ----

__global__ __launch_bounds__(256) void gather2(
    const uint* __restrict__ h1p,
    const int* __restrict__ offs, const int* __restrict__ deg,
    const int* __restrict__ ssrc,
    uint* __restrict__ z1p, int N)
{
    int lane = threadIdx.x & 63;
    int i = blockIdx.x * 4 + (threadIdx.x >> 6);
    if (i >= N) return;
    int p = lane & 31, half = lane >> 5;
    int st = offs[i], len = deg[i];
    float c0l = 0.f, c0h = 0.f, c1l = 0.f, c1h = 0.f;
    float c2l = 0.f, c2h = 0.f, c3l = 0.f, c3h = 0.f;
    int k = 0;
    while (k < len) {
        int chunk = min(len - k, 64);
        int sv = ssrc[st + k + min(lane, chunk - 1)];
        int t = 0;
        for (; t + 8 <= chunk; t += 8) {
            int s0 = __shfl(sv, t     + half, 64);
            int s1 = __shfl(sv, t + 2 + half, 64);
            int s2 = __shfl(sv, t + 4 + half, 64);
            int s3 = __shfl(sv, t + 6 + half, 64);
            uint d0 = h1p[(size_t)s0 * 32 + p];
            uint d1 = h1p[(size_t)s1 * 32 + p];
            uint d2 = h1p[(size_t)s2 * 32 + p];
            uint d3 = h1p[(size_t)s3 * 32 + p];
            __half2 h0 = *(__half2*)&d0, h1_ = *(__half2*)&d1;
            __half2 h2 = *(__half2*)&d2, h3 = *(__half2*)&d3;
            c0l += __low2float(h0); c0h += __high2float(h0);
            c1l += __low2float(h1_); c1h += __high2float(h1_);
            c2l += __low2float(h2); c2h += __high2float(h2);
            c3l += __low2float(h3); c3h += __high2float(h3);
        }
        for (; t + 2 <= chunk; t += 2) {
            int s0 = __shfl(sv, t + half, 64);
            uint d0 = h1p[(size_t)s0 * 32 + p];
            __half2 h0 = *(__half2*)&d0;
            c0l += __low2float(h0); c0h += __high2float(h0);
        }
        if (t < chunk) {
            int s0 = __shfl(sv, t, 64);
            uint d0 = h1p[(size_t)s0 * 32 + p];
            __half2 h0 = *(__half2*)&d0;
            if (half == 0) { c0l += __low2float(h0); c0h += __high2float(h0); }
        }
        k += chunk;
    }
    float zl = (c0l + c1l) + (c2l + c3l);
    float zh = (c0h + c1h) + (c2h + c3h);
    zl += __shfl_xor(zl, 32, 64);
    zh += __shfl_xor(zh, 32, 64);
    uint ds = h1p[(size_t)i * 32 + p];
    __half2 hs = *(__half2*)&ds;
    zl += __low2float(hs);
    zh += __high2float(hs);
    if (half == 0) {
        __half2 zo = __halves2half2(__float2half(zl), __float2half(zh));
        z1p[(size_t)i * 32 + p] = *(uint*)&zo;
    }
}

// ---------------- mlp2 + pooling ----------------

__global__ __launch_bounds__(256) void mlp2pool(
    const uint* __restrict__ z1p,
    const float* __restrict__ W2a, const float* __restrict__ b2a,
    const float* __restrict__ W2b, const float* __restrict__ b2b,
    const int* __restrict__ batch,
    float* __restrict__ sums, float* __restrict__ counts, int N)
{
    __shared__ float Wa[64 * 64];
    __shared__ float Wb[64 * 64];
    for (int i = threadIdx.x; i < 64 * 64; i += 256) {
        Wa[i] = W2a[i];
        Wb[i] = W2b[i];
    }
    __syncthreads();

    int lane = threadIdx.x & 63;
    int wv = blockIdx.x * 4 + (threadIdx.x >> 6);
    int i0 = wv * 4;
    if (i0 >= N) return;
    float ba = b2a[lane], bb = b2b[lane];

    float zl[4];
#pragma unroll
    for (int n = 0; n < 4; n++) {
        uint d = z1p[(size_t)(i0 + n) * 32 + (lane >> 1)];
        __half2 h = *(__half2*)&d;
        zl[n] = (lane & 1) ? __high2float(h) : __low2float(h);
    }

    float t[4], o[4];
#pragma unroll
    for (int n = 0; n < 4; n++) t[n] = ba;
#pragma unroll
    for (int k = 0; k < 64; k++) {
        float wa = Wa[k * 64 + lane];
#pragma unroll
        for (int n = 0; n < 4; n++) t[n] += rlane(zl[n], k) * wa;
    }
#pragma unroll
    for (int n = 0; n < 4; n++) { t[n] = fmaxf(t[n], 0.f); o[n] = bb; }
#pragma unroll
    for (int k = 0; k < 64; k++) {
        float wb = Wb[k * 64 + lane];
#pragma unroll
        for (int n = 0; n < 4; n++) o[n] += rlane(t[n], k) * wb;
    }

    int gcur = batch[i0]; float ps = 0.f; int cnt = 0;
#pragma unroll
    for (int n = 0; n < 4; n++) {
        float h2 = fmaxf(o[n], 0.f);
        int gi = batch[i0 + n];
        if (gi != gcur) {
            atomicAdd(&sums[gcur * 64 + lane], ps);
            if (lane == 0) atomicAdd(&counts[gcur], (float)cnt);
            gcur = gi; ps = 0.f; cnt = 0;
        }
        ps += h2; cnt++;
    }
    atomicAdd(&sums[gcur * 64 + lane], ps);
    if (lane == 0) atomicAdd(&counts[gcur], (float)cnt);
}

__global__ __launch_bounds__(256) void gin_final(
    const float* __restrict__ sums, const float* __restrict__ counts,
    const float* __restrict__ Wlin, const float* __restrict__ blin,
    float* __restrict__ out, int G)
{
    int lane = threadIdx.x & 63;
    int g    = blockIdx.x * 4 + (threadIdx.x >> 6);
    if (g < G) {
        float v = sums[g * 64 + lane] * Wlin[lane];
#pragma unroll
        for (int off = 32; off > 0; off >>= 1) v += __shfl_down(v, off, 64);
        if (lane == 0) out[g] = v / fmaxf(counts[g], 1.0f) + blin[0];
    }
}

extern "C" void kernel_launch(void* const* d_in, const int* in_sizes, int n_in,
                              void* d_out, int out_size, void* d_ws, size_t ws_size,
                              hipStream_t stream) {
    const float* x    = (const float*)d_in[0];
    const float* pos  = (const float*)d_in[1];
    const int*   ei   = (const int*)d_in[2];
    const int*   batch= (const int*)d_in[3];
    const float* W1a  = (const float*)d_in[4];
    const float* b1a  = (const float*)d_in[5];
    const float* W1b  = (const float*)d_in[6];
    const float* b1b  = (const float*)d_in[7];
    const float* W2a  = (const float*)d_in[8];
    const float* b2a  = (const float*)d_in[9];
    const float* W2b  = (const float*)d_in[10];
    const float* b2b  = (const float*)d_in[11];
    const float* Wlin = (const float*)d_in[12];
    const float* blin = (const float*)d_in[13];
    float* out = (float*)d_out;

    const int N = in_sizes[0] / 11;     // 50000
    const int E = in_sizes[2] / 2;      // 800000
    const int G = out_size;             // 2500

    const int* src = ei;
    const int* dst = ei + E;
    const int nbk = (N + (1 << BSH) - 1) >> BSH;   // 196
    const int neb = (E + EPB - 1) / EPB;           // 196

    // Workspace:
    // [sums|counts|bkt_cnt](memset) |offs|deg|bkt_off|bkt_cur|ssrc|h1p|
    // zreg { z0 (N*16 f32) / z1p (N*32 u32) / pairs (E ull) } -- time-disjoint
    char* ws = (char*)d_ws;
    size_t o = 0;
    float* sums    = (float*)(ws + o); o += (size_t)G * 64 * 4;
    float* counts  = (float*)(ws + o); o += (((size_t)G + 63) & ~(size_t)63) * 4;
    int*   bkt_cnt = (int*)(ws + o);   o += NBKMAX * 4;
    size_t zero_bytes = o;
    int*   offs    = (int*)(ws + o);   o += (size_t)N * 4;
    int*   deg     = (int*)(ws + o);   o += (size_t)N * 4;
    int*   bkt_off = (int*)(ws + o);   o += (NBKMAX + 1) * 4;
    int*   bkt_cur = (int*)(ws + o);   o += NBKMAX * 4;
    int*   ssrc    = (int*)(ws + o);   o += (size_t)E * 4;
    o = (o + 255) & ~(size_t)255;
    uint*  h1p     = (uint*)(ws + o);  o += (size_t)N * 32 * 4;
    o = (o + 255) & ~(size_t)255;
    float* z0      = (float*)(ws + o); // N*16 f32 (3.2 MB)
    uint*  z1p     = (uint*)(ws + o);  // N*32 u32 (6.4 MB)
    ull*   pairs   = (ull*)(ws + o);   // E*8 B (6.4 MB) -- dead before gather1

    hipMemsetAsync(ws, 0, zero_bytes, stream);

    bucket_hist<<<neb, 256, 0, stream>>>(dst, bkt_cnt, nbk, E);
    scan_small<<<1, 256, 0, stream>>>(bkt_cnt, bkt_off, bkt_cur, nbk);
    bin_pairs<<<neb, 256, 0, stream>>>(src, dst, bkt_cur, pairs, nbk, E);
    bucket_build<<<nbk, 256, 0, stream>>>(pairs, bkt_off, offs, deg, ssrc, N);

    gather1<<<(N + 3) / 4, 256, 0, stream>>>(x, pos, offs, deg, ssrc, z0, N);
    mlp1<<<(N + 15) / 16, 256, 0, stream>>>(z0, W1a, b1a, W1b, b1b, h1p, N);
    gather2<<<(N + 3) / 4, 256, 0, stream>>>(h1p, offs, deg, ssrc, z1p, N);
    mlp2pool<<<(N + 15) / 16, 256, 0, stream>>>(
        z1p, W2a, b2a, W2b, b2b, batch, sums, counts, N);

    gin_final<<<(G + 3) / 4, 256, 0, stream>>>(
        sums, counts, Wlin, blin, out, G);
}

// Round 8
// 225.802 us; speedup vs baseline: 1.2836x; 1.0234x over previous
//
#include <hip/hip_runtime.h>
#include <hip/hip_fp16.h>

// GIN: 2x GINConv(eps=0, MLP 2-layer H=64) + global mean pool + linear.
// N=50000, E=800000, G=2500.
//
// R7: gathers rebuilt for maximum rows-in-flight per instruction:
//  - gather2: dwordx4/lane, 8 lanes/row -> 8 rows per load instruction
//  - gather1: x,pos pre-packed to f16 rows (32B); dwordx2/lane, 4 lanes/row
//    -> 16 rows per load instruction (typical deg=16 node = ONE load)
//  - CSR pairs packed to u32 (dst_local<<16 | src; requires N<65536)
// CSR build remains zero-global-atomic (R6 bucket scheme).

typedef unsigned int uint;

#define BSH  8           // bucket = 256 nodes
#define NBKMAX 256       // >= ceil(50000/256)=196
#define EPB  4096        // edges per block in hist/bin passes

__device__ __forceinline__ float rlane(float v, int k) {
    return __uint_as_float(__builtin_amdgcn_readlane(__float_as_uint(v), k));
}
__device__ __forceinline__ void addu(float* a, uint d) {
    __half2 h = *(__half2*)&d;
    a[0] += __low2float(h);
    a[1] += __high2float(h);
}

// ---------------- pack x,pos -> f16 rows [N x 32B] ----------------

__global__ __launch_bounds__(256) void pack_x(
    const float* __restrict__ x, const float* __restrict__ pos,
    uint2* __restrict__ xp2, int N)
{
    int i = blockIdx.x * 256 + threadIdx.x;
    if (i >= N) return;
    float v[16];
#pragma unroll
    for (int k = 0; k < 11; k++) v[k] = x[(size_t)i * 11 + k];
    v[11] = pos[(size_t)i * 3 + 0];
    v[12] = pos[(size_t)i * 3 + 1];
    v[13] = pos[(size_t)i * 3 + 2];
    v[14] = 0.f; v[15] = 0.f;
#pragma unroll
    for (int c = 0; c < 4; c++) {
        __half2 l = __floats2half2_rn(v[4 * c],     v[4 * c + 1]);
        __half2 h = __floats2half2_rn(v[4 * c + 2], v[4 * c + 3]);
        uint2 u;
        u.x = *(uint*)&l;
        u.y = *(uint*)&h;
        xp2[(size_t)i * 4 + c] = u;
    }
}

// ---------------- bucket histogram (LDS-privatized) ----------------

__global__ __launch_bounds__(256) void bucket_hist(
    const int* __restrict__ dst, int* __restrict__ bkt_cnt, int nbk, int E)
{
    __shared__ int lb[NBKMAX];
    for (int i = threadIdx.x; i < nbk; i += 256) lb[i] = 0;
    __syncthreads();
    int e0 = blockIdx.x * EPB + threadIdx.x;
#pragma unroll
    for (int j = 0; j < EPB / 256; j++) {
        int e = e0 + j * 256;
        if (e < E) atomicAdd(&lb[dst[e] >> BSH], 1);
    }
    __syncthreads();
    for (int i = threadIdx.x; i < nbk; i += 256) {
        int c = lb[i];
        if (c) atomicAdd(&bkt_cnt[i], c);
    }
}

// ---------------- bucket-offset scan (single block) ----------------

__global__ __launch_bounds__(256) void scan_small(
    const int* __restrict__ cnt, int* __restrict__ off,
    int* __restrict__ cur, int nbk)
{
    __shared__ int wsum[4];
    int i = threadIdx.x;
    int v = (i < nbk) ? cnt[i] : 0;
    int lane = threadIdx.x & 63, w = threadIdx.x >> 6;
    int s = v;
#pragma unroll
    for (int off2 = 1; off2 < 64; off2 <<= 1) {
        int t = __shfl_up(s, off2, 64);
        if (lane >= off2) s += t;
    }
    if (lane == 63) wsum[w] = s;
    __syncthreads();
    int add = 0;
    for (int j = 0; j < w; j++) add += wsum[j];
    int incl = s + add;
    if (i < nbk) { off[i] = incl - v; cur[i] = incl - v; }
    if (i == nbk - 1) off[nbk] = incl;   // == E
}

// ---------------- pass 1: bin edges into bucket-contiguous runs ----------------

__global__ __launch_bounds__(256) void bin_pairs(
    const int* __restrict__ src, const int* __restrict__ dst,
    int* __restrict__ bkt_cur, uint* __restrict__ pairs, int nbk, int E)
{
    __shared__ int lcnt[NBKMAX];
    __shared__ int lbase[NBKMAX];
    for (int i = threadIdx.x; i < nbk; i += 256) lcnt[i] = 0;
    __syncthreads();
    int e0 = blockIdx.x * EPB + threadIdx.x;
    uint pv[EPB / 256];
    int  rk[EPB / 256], bk[EPB / 256];
#pragma unroll
    for (int j = 0; j < EPB / 256; j++) {
        int e = e0 + j * 256;
        bk[j] = -1;
        if (e < E) {
            int s = src[e];
            int d = dst[e];
            bk[j] = d >> BSH;
            pv[j] = ((uint)(d & ((1 << BSH) - 1)) << 16) | (uint)s;  // N<65536
            rk[j] = atomicAdd(&lcnt[bk[j]], 1);
        }
    }
    __syncthreads();
    for (int i = threadIdx.x; i < nbk; i += 256) {
        int c = lcnt[i];
        lbase[i] = c ? atomicAdd(&bkt_cur[i], c) : 0;
    }
    __syncthreads();
#pragma unroll
    for (int j = 0; j < EPB / 256; j++) {
        if (bk[j] >= 0)
            pairs[(size_t)lbase[bk[j]] + rk[j]] = pv[j];
    }
}

// ---------------- pass 2: per-bucket deg/offs/ssrc (all LDS-local) ----------

__global__ __launch_bounds__(256) void bucket_build(
    const uint* __restrict__ pairs, const int* __restrict__ bkt_off,
    int* __restrict__ offs, int* __restrict__ deg,
    int* __restrict__ ssrc, int N)
{
    __shared__ int cnt[1 << BSH];
    __shared__ int cur[1 << BSH];
    __shared__ int wsum[4];
    int b = blockIdx.x;
    int nbase = b << BSH;
    int nn = min(1 << BSH, N - nbase);
    cnt[threadIdx.x] = 0;
    __syncthreads();
    int start = bkt_off[b], end = bkt_off[b + 1];
    for (int e = start + threadIdx.x; e < end; e += 256)
        atomicAdd(&cnt[pairs[e] >> 16], 1);
    __syncthreads();
    int v = cnt[threadIdx.x];
    int lane = threadIdx.x & 63, w = threadIdx.x >> 6;
    int s = v;
#pragma unroll
    for (int off2 = 1; off2 < 64; off2 <<= 1) {
        int t = __shfl_up(s, off2, 64);
        if (lane >= off2) s += t;
    }
    if (lane == 63) wsum[w] = s;
    __syncthreads();
    int add = 0;
    for (int j = 0; j < w; j++) add += wsum[j];
    int gofs = start + (s + add - v);
    if (threadIdx.x < nn) {
        offs[nbase + threadIdx.x] = gofs;
        deg[nbase + threadIdx.x]  = v;
    }
    cur[threadIdx.x] = gofs;
    __syncthreads();
    for (int e = start + threadIdx.x; e < end; e += 256) {
        uint pr = pairs[e];
        int p = atomicAdd(&cur[pr >> 16], 1);
        ssrc[p] = (int)(pr & 0xffffu);
    }
}

// ---------------- gather1: z0 = self + sum_nbr xp, 16 rows/load ----------------

__global__ __launch_bounds__(256) void gather1(
    const uint2* __restrict__ xp2,
    const int* __restrict__ offs, const int* __restrict__ deg,
    const int* __restrict__ ssrc,
    float4* __restrict__ z04, int N)
{
    int lane = threadIdx.x & 63;
    int i = blockIdx.x * 4 + (threadIdx.x >> 6);
    if (i >= N) return;
    int j = lane >> 2;           // row slot 0..15
    int c = lane & 3;            // dword-pair: features 4c..4c+3
    int st = offs[i], len = deg[i];
    float a[4] = {0.f, 0.f, 0.f, 0.f};
    int k = 0;
    while (k < len) {
        int chunk = min(len - k, 64);
        int sv = ssrc[st + k + min(lane, chunk - 1)];
        int t = 0;
        for (; t + 32 <= chunk; t += 32) {       // 32 rows / 2 loads
            int sA = __shfl(sv, t + j, 64);
            int sB = __shfl(sv, t + 16 + j, 64);
            uint2 A = xp2[(size_t)sA * 4 + c];
            uint2 B = xp2[(size_t)sB * 4 + c];
            addu(a + 0, A.x); addu(a + 2, A.y);
            addu(a + 0, B.x); addu(a + 2, B.y);
        }
        for (; t + 16 <= chunk; t += 16) {       // 16 rows / 1 load
            int sA = __shfl(sv, t + j, 64);
            uint2 A = xp2[(size_t)sA * 4 + c];
            addu(a + 0, A.x); addu(a + 2, A.y);
        }
        if (t < chunk) {                         // tail r<16 rows, masked
            int r = chunk - t;
            int sA = __shfl(sv, t + min(j, r - 1), 64);
            uint2 A = xp2[(size_t)sA * 4 + c];
            if (j < r) { addu(a + 0, A.x); addu(a + 2, A.y); }
        }
        k += chunk;
    }
#pragma unroll
    for (int m = 4; m < 64; m <<= 1)
#pragma unroll
        for (int d = 0; d < 4; d++) a[d] += __shfl_xor(a[d], m, 64);
    uint2 S = xp2[(size_t)i * 4 + c];            // self
    addu(a + 0, S.x); addu(a + 2, S.y);
    if (lane < 4) {                              // c == lane
        float4 f; f.x = a[0]; f.y = a[1]; f.z = a[2]; f.w = a[3];
        z04[(size_t)i * 4 + lane] = f;
    }
}

// ---------------- mlp1: h1 = relu(MLP(z0)) -> packed f16 [N x 32 dwords] ----

__global__ __launch_bounds__(256) void mlp1(
    const float* __restrict__ z0,
    const float* __restrict__ W1a, const float* __restrict__ b1a,
    const float* __restrict__ W1b, const float* __restrict__ b1b,
    uint* __restrict__ h1p, int N)
{
    __shared__ float Wa[14 * 64];
    __shared__ float Wb[64 * 64];
    for (int i = threadIdx.x; i < 14 * 64; i += 256) Wa[i] = W1a[i];
    for (int i = threadIdx.x; i < 64 * 64; i += 256) Wb[i] = W1b[i];
    __syncthreads();

    int lane = threadIdx.x & 63;
    int wv = blockIdx.x * 4 + (threadIdx.x >> 6);
    int i0 = wv * 4;
    if (i0 >= N) return;

    float zl = z0[(size_t)i0 * 16 + lane];
    float ba = b1a[lane], bb = b1b[lane];

    float t[4], o[4];
#pragma unroll
    for (int n = 0; n < 4; n++) t[n] = ba;
#pragma unroll
    for (int k = 0; k < 14; k++) {
        float wa = Wa[k * 64 + lane];
#pragma unroll
        for (int n = 0; n < 4; n++) t[n] += rlane(zl, n * 16 + k) * wa;
    }
#pragma unroll
    for (int n = 0; n < 4; n++) { t[n] = fmaxf(t[n], 0.f); o[n] = bb; }
#pragma unroll
    for (int k = 0; k < 64; k++) {
        float wb = Wb[k * 64 + lane];
#pragma unroll
        for (int n = 0; n < 4; n++) o[n] += rlane(t[n], k) * wb;
    }
#pragma unroll
    for (int n = 0; n < 4; n++) o[n] = fmaxf(o[n], 0.f);  // outer relu L1

    int p = lane & 31, half = lane >> 5;
#pragma unroll
    for (int pr = 0; pr < 2; pr++) {
        float lo0 = __shfl(o[2 * pr],     2 * p,     64);
        float hi0 = __shfl(o[2 * pr],     2 * p + 1, 64);
        float lo1 = __shfl(o[2 * pr + 1], 2 * p,     64);
        float hi1 = __shfl(o[2 * pr + 1], 2 * p + 1, 64);
        float lo = half ? lo1 : lo0;
        float hi = half ? hi1 : hi0;
        __half2 h = __halves2half2(__float2half(lo), __float2half(hi));
        h1p[(size_t)(i0 + 2 * pr + half) * 32 + p] = *(uint*)&h;
    }
}

// ---------------- gather2: z1 = self + sum_nbr h1, 8 rows/load ----------------

__global__ __launch_bounds__(256) void gather2(
    const uint4* __restrict__ h4,
    const int* __restrict__ offs, const int* __restrict__ deg,
    const int* __restrict__ ssrc,
    uint4* __restrict__ z4, int N)
{
    int lane = threadIdx.x & 63;
    int i = blockIdx.x * 4 + (threadIdx.x >> 6);
    if (i >= N) return;
    int j = lane >> 3;           // row slot 0..7
    int q = lane & 7;            // uint4 index: features 8q..8q+7
    int st = offs[i], len = deg[i];
    float a[8] = {0.f, 0.f, 0.f, 0.f, 0.f, 0.f, 0.f, 0.f};
    int k = 0;
    while (k < len) {
        int chunk = min(len - k, 64);
        int sv = ssrc[st + k + min(lane, chunk - 1)];
        int t = 0;
        for (; t + 32 <= chunk; t += 32) {       // 32 rows / 4 loads
            int sA = __shfl(sv, t + j, 64);
            int sB = __shfl(sv, t + 8 + j, 64);
            int sC = __shfl(sv, t + 16 + j, 64);
            int sD = __shfl(sv, t + 24 + j, 64);
            uint4 A = h4[(size_t)sA * 8 + q];
            uint4 B = h4[(size_t)sB * 8 + q];
            uint4 C = h4[(size_t)sC * 8 + q];
            uint4 D = h4[(size_t)sD * 8 + q];
            addu(a + 0, A.x); addu(a + 2, A.y); addu(a + 4, A.z); addu(a + 6, A.w);
            addu(a + 0, B.x); addu(a + 2, B.y); addu(a + 4, B.z); addu(a + 6, B.w);
            addu(a + 0, C.x); addu(a + 2, C.y); addu(a + 4, C.z); addu(a + 6, C.w);
            addu(a + 0, D.x); addu(a + 2, D.y); addu(a + 4, D.z); addu(a + 6, D.w);
        }
        for (; t + 16 <= chunk; t += 16) {       // 16 rows / 2 loads
            int sA = __shfl(sv, t + j, 64);
            int sB = __shfl(sv, t + 8 + j, 64);
            uint4 A = h4[(size_t)sA * 8 + q];
            uint4 B = h4[(size_t)sB * 8 + q];
            addu(a + 0, A.x); addu(a + 2, A.y); addu(a + 4, A.z); addu(a + 6, A.w);
            addu(a + 0, B.x); addu(a + 2, B.y); addu(a + 4, B.z); addu(a + 6, B.w);
        }
        for (; t + 8 <= chunk; t += 8) {         // 8 rows / 1 load
            int sA = __shfl(sv, t + j, 64);
            uint4 A = h4[(size_t)sA * 8 + q];
            addu(a + 0, A.x); addu(a + 2, A.y); addu(a + 4, A.z); addu(a + 6, A.w);
        }
        if (t < chunk) {                         // tail r<8 rows, masked
            int r = chunk - t;
            int sA = __shfl(sv, t + min(j, r - 1), 64);
            uint4 A = h4[(size_t)sA * 8 + q];
            if (j < r) {
                addu(a + 0, A.x); addu(a + 2, A.y);
                addu(a + 4, A.z); addu(a + 6, A.w);
            }
        }
        k += chunk;
    }
#pragma unroll
    for (int m = 8; m < 64; m <<= 1)
#pragma unroll
        for (int d = 0; d < 8; d++) a[d] += __shfl_xor(a[d], m, 64);
    uint4 S = h4[(size_t)i * 8 + q];             // self
    addu(a + 0, S.x); addu(a + 2, S.y); addu(a + 4, S.z); addu(a + 6, S.w);
    if (lane < 8) {                              // q == lane
        __half2 p0 = __floats2half2_rn(a[0], a[1]);
        __half2 p1 = __floats2half2_rn(a[2], a[3]);
        __half2 p2 = __floats2half2_rn(a[4], a[5]);
        __half2 p3 = __floats2half2_rn(a[6], a[7]);
        uint4 o4;
        o4.x = *(uint*)&p0; o4.y = *(uint*)&p1;
        o4.z = *(uint*)&p2; o4.w = *(uint*)&p3;
        z4[(size_t)i * 8 + lane] = o4;
    }
}

// ---------------- mlp2 + pooling ----------------

__global__ __launch_bounds__(256) void mlp2pool(
    const uint* __restrict__ z1p,
    const float* __restrict__ W2a, const float* __restrict__ b2a,
    const float* __restrict__ W2b, const float* __restrict__ b2b,
    const int* __restrict__ batch,
    float* __restrict__ sums, float* __restrict__ counts, int N)
{
    __shared__ float Wa[64 * 64];
    __shared__ float Wb[64 * 64];
    for (int i = threadIdx.x; i < 64 * 64; i += 256) {
        Wa[i] = W2a[i];
        Wb[i] = W2b[i];
    }
    __syncthreads();

    int lane = threadIdx.x & 63;
    int wv = blockIdx.x * 4 + (threadIdx.x >> 6);
    int i0 = wv * 4;
    if (i0 >= N) return;
    float ba = b2a[lane], bb = b2b[lane];

    float zl[4];
#pragma unroll
    for (int n = 0; n < 4; n++) {
        uint d = z1p[(size_t)(i0 + n) * 32 + (lane >> 1)];
        __half2 h = *(__half2*)&d;
        zl[n] = (lane & 1) ? __high2float(h) : __low2float(h);
    }

    float t[4], o[4];
#pragma unroll
    for (int n = 0; n < 4; n++) t[n] = ba;
#pragma unroll
    for (int k = 0; k < 64; k++) {
        float wa = Wa[k * 64 + lane];
#pragma unroll
        for (int n = 0; n < 4; n++) t[n] += rlane(zl[n], k) * wa;
    }
#pragma unroll
    for (int n = 0; n < 4; n++) { t[n] = fmaxf(t[n], 0.f); o[n] = bb; }
#pragma unroll
    for (int k = 0; k < 64; k++) {
        float wb = Wb[k * 64 + lane];
#pragma unroll
        for (int n = 0; n < 4; n++) o[n] += rlane(t[n], k) * wb;
    }

    int gcur = batch[i0]; float ps = 0.f; int cnt = 0;
#pragma unroll
    for (int n = 0; n < 4; n++) {
        float h2 = fmaxf(o[n], 0.f);
        int gi = batch[i0 + n];
        if (gi != gcur) {
            atomicAdd(&sums[gcur * 64 + lane], ps);
            if (lane == 0) atomicAdd(&counts[gcur], (float)cnt);
            gcur = gi; ps = 0.f; cnt = 0;
        }
        ps += h2; cnt++;
    }
    atomicAdd(&sums[gcur * 64 + lane], ps);
    if (lane == 0) atomicAdd(&counts[gcur], (float)cnt);
}

__global__ __launch_bounds__(256) void gin_final(
    const float* __restrict__ sums, const float* __restrict__ counts,
    const float* __restrict__ Wlin, const float* __restrict__ blin,
    float* __restrict__ out, int G)
{
    int lane = threadIdx.x & 63;
    int g    = blockIdx.x * 4 + (threadIdx.x >> 6);
    if (g < G) {
        float v = sums[g * 64 + lane] * Wlin[lane];
#pragma unroll
        for (int off = 32; off > 0; off >>= 1) v += __shfl_down(v, off, 64);
        if (lane == 0) out[g] = v / fmaxf(counts[g], 1.0f) + blin[0];
    }
}

extern "C" void kernel_launch(void* const* d_in, const int* in_sizes, int n_in,
                              void* d_out, int out_size, void* d_ws, size_t ws_size,
                              hipStream_t stream) {
    const float* x    = (const float*)d_in[0];
    const float* pos  = (const float*)d_in[1];
    const int*   ei   = (const int*)d_in[2];
    const int*   batch= (const int*)d_in[3];
    const float* W1a  = (const float*)d_in[4];
    const float* b1a  = (const float*)d_in[5];
    const float* W1b  = (const float*)d_in[6];
    const float* b1b  = (const float*)d_in[7];
    const float* W2a  = (const float*)d_in[8];
    const float* b2a  = (const float*)d_in[9];
    const float* W2b  = (const float*)d_in[10];
    const float* b2b  = (const float*)d_in[11];
    const float* Wlin = (const float*)d_in[12];
    const float* blin = (const float*)d_in[13];
    float* out = (float*)d_out;

    const int N = in_sizes[0] / 11;     // 50000 (must be < 65536 for u32 pairs)
    const int E = in_sizes[2] / 2;      // 800000
    const int G = out_size;             // 2500

    const int* src = ei;
    const int* dst = ei + E;
    const int nbk = (N + (1 << BSH) - 1) >> BSH;   // 196
    const int neb = (E + EPB - 1) / EPB;           // 196

    // Workspace:
    // [sums|counts|bkt_cnt](memset) |offs|deg|bkt_off|bkt_cur|ssrc|h1p|xp|
    // zunion { pairs (E u32) / z0 (N*16 f32) / z1p (N*32 u32) } time-disjoint
    char* ws = (char*)d_ws;
    size_t o = 0;
    float* sums    = (float*)(ws + o); o += (size_t)G * 64 * 4;
    float* counts  = (float*)(ws + o); o += (((size_t)G + 63) & ~(size_t)63) * 4;
    int*   bkt_cnt = (int*)(ws + o);   o += NBKMAX * 4;
    size_t zero_bytes = o;
    int*   offs    = (int*)(ws + o);   o += (size_t)N * 4;
    int*   deg     = (int*)(ws + o);   o += (size_t)N * 4;
    int*   bkt_off = (int*)(ws + o);   o += (NBKMAX + 1) * 4;
    int*   bkt_cur = (int*)(ws + o);   o += NBKMAX * 4;
    int*   ssrc    = (int*)(ws + o);   o += (size_t)E * 4;
    o = (o + 255) & ~(size_t)255;
    uint*  h1p     = (uint*)(ws + o);  o += (size_t)N * 32 * 4;
    o = (o + 255) & ~(size_t)255;
    uint2* xp2     = (uint2*)(ws + o); o += (size_t)N * 32;
    o = (o + 255) & ~(size_t)255;
    uint*  pairs   = (uint*)(ws + o);  // E u32 (3.2 MB)  } dead before gather1
    float* z0      = (float*)(ws + o); // N*16 f32 (3.2MB)} dead after mlp1
    uint*  z1p     = (uint*)(ws + o);  // N*32 u32 (6.4MB)} written by gather2

    hipMemsetAsync(ws, 0, zero_bytes, stream);

    pack_x<<<(N + 255) / 256, 256, 0, stream>>>(x, pos, xp2, N);
    bucket_hist<<<neb, 256, 0, stream>>>(dst, bkt_cnt, nbk, E);
    scan_small<<<1, 256, 0, stream>>>(bkt_cnt, bkt_off, bkt_cur, nbk);
    bin_pairs<<<neb, 256, 0, stream>>>(src, dst, bkt_cur, pairs, nbk, E);
    bucket_build<<<nbk, 256, 0, stream>>>(pairs, bkt_off, offs, deg, ssrc, N);

    gather1<<<(N + 3) / 4, 256, 0, stream>>>(
        xp2, offs, deg, ssrc, (float4*)z0, N);
    mlp1<<<(N + 15) / 16, 256, 0, stream>>>(z0, W1a, b1a, W1b, b1b, h1p, N);
    gather2<<<(N + 3) / 4, 256, 0, stream>>>(
        (const uint4*)h1p, offs, deg, ssrc, (uint4*)z1p, N);
    mlp2pool<<<(N + 15) / 16, 256, 0, stream>>>(
        z1p, W2a, b2a, W2b, b2b, batch, sums, counts, N);

    gin_final<<<(G + 3) / 4, 256, 0, stream>>>(
        sums, counts, Wlin, blin, out, G);
}